// Round 4
// baseline (68.865 us; speedup 1.0000x reference)
//
#include <hip/hip_runtime.h>

#define NCH 256
#define ROIS_ELEMS 50176000              // 800*7*7*1280

typedef float vf2 __attribute__((ext_vector_type(2)));

// Two waves per (box n, level l, row py): each covers 128 of 256 channels.
// 800 boxes * 5 levels * 7 rows * 2 halves = 56000 waves; 4/block -> 14000 blocks.
__global__ __launch_bounds__(256) void roi_row_kernel(
    const float* __restrict__ boxes,   // [800,4] image-space (y1,x1,y2,x2)
    const float* __restrict__ fm0,
    const float* __restrict__ fm1,
    const float* __restrict__ fm2,
    const float* __restrict__ fm3,
    const float* __restrict__ fm4,
    float* __restrict__ out,           // [800,7,7,1280]
    float* __restrict__ out_ids)       // [800] written as float
{
    const int wave = threadIdx.x >> 6;
    const int lane = threadIdx.x & 63;

    // XCD-chunked bijective swizzle: 14000 = 8 * 1750 exactly.
    const int bswz = (blockIdx.x & 7) * 1750 + (blockIdx.x >> 3);
    const int wg   = bswz * 4 + wave;          // [0, 56000)
    const int row  = wg >> 1;                  // [0, 28000)
    const int half = wg & 1;                   // channel half: [0,128) or [128,256)

    const int n   = row / 35;                  // box index [0,800)
    const int rem = row - n * 35;
    const int l   = rem / 7;                   // level [0,5)
    const int py  = rem - l * 7;               // output row [0,7)

    const float* fm;
    switch (l) {
        case 0: fm = fm0; break;
        case 1: fm = fm1; break;
        case 2: fm = fm2; break;
        case 3: fm = fm3; break;
        default: fm = fm4; break;
    }
    const int H = 128 >> l;                    // square feature map
    const float Hm1 = (float)(H - 1);
    const float scale = (float)((8 << l) * (H - 1));   // exact in f32

    const int img = n / 100;
    const float y1 = boxes[n * 4 + 0];
    const float x1 = boxes[n * 4 + 1];
    const float y2 = boxes[n * 4 + 2];
    const float x2 = boxes[n * 4 + 3];

    // Replicate reference numerics (explicit rounding, no fp-contract).
    const float y1n = __fdiv_rn(y1, scale);
    const float y2n = __fdiv_rn(y2, scale);
    const float x1n = __fdiv_rn(x1, scale);
    const float x2n = __fdiv_rn(x2, scale);

    const float fy = __fdiv_rn((float)py, 6.0f);
    const float ys = __fmul_rn(__fadd_rn(y1n, __fmul_rn(__fsub_rn(y2n, y1n), fy)), Hm1);
    const bool  vy = (ys >= 0.0f) && (ys <= Hm1);
    const float y0f = floorf(ys);
    const float wy  = ys - y0f;
    const float owy = 1.0f - wy;
    const int y0  = (int)fminf(fmaxf(y0f,        0.0f), Hm1);
    const int y1i = (int)fminf(fmaxf(y0f + 1.0f, 0.0f), Hm1);

    const int rowTop = (img * H + y0 ) * H;
    const int rowBot = (img * H + y1i) * H;
    const int chOff  = half * 128;             // element offset of this wave's half

    // Phase 1: per-px coords + scalarized (wave-uniform) element offsets.
    float wx_[7];
    bool  vx_[7];
    int oT0[7], oT1[7], oB0[7], oB1[7];
    #pragma unroll
    for (int px = 0; px < 7; ++px) {
        const float fx = __fdiv_rn((float)px, 6.0f);
        const float xs = __fmul_rn(__fadd_rn(x1n, __fmul_rn(__fsub_rn(x2n, x1n), fx)), Hm1);
        vx_[px] = (xs >= 0.0f) && (xs <= Hm1);
        const float x0f = floorf(xs);
        wx_[px] = xs - x0f;
        const int x0  = (int)fminf(fmaxf(x0f,        0.0f), Hm1);
        const int x1i = (int)fminf(fmaxf(x0f + 1.0f, 0.0f), Hm1);
        oT0[px] = __builtin_amdgcn_readfirstlane((rowTop + x0 ) * NCH + chOff);
        oT1[px] = __builtin_amdgcn_readfirstlane((rowTop + x1i) * NCH + chOff);
        oB0[px] = __builtin_amdgcn_readfirstlane((rowBot + x0 ) * NCH + chOff);
        oB1[px] = __builtin_amdgcn_readfirstlane((rowBot + x1i) * NCH + chOff);
    }

    // Phase 2: issue all 28 corner loads (512 B each, coalesced) -> max MLP.
    vf2 v00[7], v01[7], v10[7], v11[7];
    #pragma unroll
    for (int px = 0; px < 7; ++px) {
        v00[px] = ((const vf2*)(fm + oT0[px]))[lane];
        v01[px] = ((const vf2*)(fm + oT1[px]))[lane];
        v10[px] = ((const vf2*)(fm + oB0[px]))[lane];
        v11[px] = ((const vf2*)(fm + oB1[px]))[lane];
    }

    // Phase 3: blend + non-temporal store (output is write-once).
    float* obase = out + ((n * 7 + py) * 7) * 1280 + l * NCH + chOff;
    #pragma unroll
    for (int px = 0; px < 7; ++px) {
        const float wx  = wx_[px];
        const float owx = 1.0f - wx;
        vf2 r = (v00[px] * owx + v01[px] * wx) * owy
              + (v10[px] * owx + v11[px] * wx) * wy;
        if (!(vy && vx_[px])) { r = (vf2)0.0f; }
        __builtin_nontemporal_store(r, ((vf2*)(obase + px * 1280)) + lane);
    }

    if (l == 0 && py == 0 && half == 0 && lane == 0) {
        out_ids[n] = (float)img;
    }
}

extern "C" void kernel_launch(void* const* d_in, const int* in_sizes, int n_in,
                              void* d_out, int out_size, void* d_ws, size_t ws_size,
                              hipStream_t stream) {
    const float* boxes = (const float*)d_in[0];
    const float* fm0   = (const float*)d_in[1];
    const float* fm1   = (const float*)d_in[2];
    const float* fm2   = (const float*)d_in[3];
    const float* fm3   = (const float*)d_in[4];
    const float* fm4   = (const float*)d_in[5];

    float* out     = (float*)d_out;
    float* out_ids = out + ROIS_ELEMS;

    roi_row_kernel<<<14000, 256, 0, stream>>>(boxes, fm0, fm1, fm2, fm3, fm4, out, out_ids);
}